// Round 5
// baseline (1620.200 us; speedup 1.0000x reference)
//
#include <hip/hip_runtime.h>
#include <hip/hip_bf16.h>

typedef float f32x4 __attribute__((ext_vector_type(4)));
typedef short short8 __attribute__((ext_vector_type(8)));
typedef __bf16 bf16x8 __attribute__((ext_vector_type(8)));
typedef unsigned int u32x4 __attribute__((ext_vector_type(4)));
typedef unsigned int u32x2 __attribute__((ext_vector_type(2)));

#define DI __device__ __forceinline__

constexpr int Bsz = 64;
constexpr int Fd  = 1024;
constexpr int Seq = 256;
constexpr int G4  = 4096;
constexpr int Mrows = Seq * Bsz;

DI float bf2f(unsigned short u) {
  union { unsigned int i; float f; } v; v.i = ((unsigned int)u) << 16; return v.f;
}
DI unsigned short f2bf(float f) {
  union { float ff; unsigned int i; } v; v.ff = f;
  unsigned int x = v.i;
  return (unsigned short)((x + 0x7fffu + ((x >> 16) & 1u)) >> 16);
}
DI float sigm(float x) { return 1.f / (1.f + __expf(-x)); }
DI float tanhfast(float x) {
  float e = __expf(-2.f * fabsf(x));
  float t = (1.f - e) / (1.f + e);
  return x < 0.f ? -t : t;
}
DI f32x4 mfma16(short8 a, short8 b, f32x4 c) {
  return __builtin_amdgcn_mfma_f32_16x16x32_bf16(
      __builtin_bit_cast(bf16x8, a), __builtin_bit_cast(bf16x8, b), c, 0, 0, 0);
}
DI unsigned int umin2(unsigned int a, unsigned int b) { return a < b ? a : b; }

// 4 coherent 16B loads issued in parallel, one waitcnt (MALL round trip).
DI void ld4x4_sys(const unsigned int* p0, const unsigned int* p1,
                  const unsigned int* p2, const unsigned int* p3,
                  u32x4& a, u32x4& b, u32x4& c, u32x4& d) {
  asm volatile(
      "global_load_dwordx4 %0, %4, off sc0 sc1\n\t"
      "global_load_dwordx4 %1, %5, off sc0 sc1\n\t"
      "global_load_dwordx4 %2, %6, off sc0 sc1\n\t"
      "global_load_dwordx4 %3, %7, off sc0 sc1\n\t"
      "s_waitcnt vmcnt(0)"
      : "=&v"(a), "=&v"(b), "=&v"(c), "=&v"(d)
      : "v"(p0), "v"(p1), "v"(p2), "v"(p3)
      : "memory");
}

// ---------- transpose x [B][F][S] f32 -> xs [S][B][F] bf16 ----------
__global__ void k_tx(const float* __restrict__ x, unsigned short* __restrict__ xs) {
  __shared__ float t[32][33];
  int b = blockIdx.z, f0 = blockIdx.y * 32, s0 = blockIdx.x * 32;
  int tx = threadIdx.x & 31, ty = threadIdx.x >> 5;
#pragma unroll
  for (int i = 0; i < 32; i += 8)
    t[ty + i][tx] = x[((size_t)b * Fd + f0 + ty + i) * Seq + s0 + tx];
  __syncthreads();
#pragma unroll
  for (int i = 0; i < 32; i += 8) {
    int s = s0 + ty + i, f = f0 + tx;
    xs[((size_t)s * Bsz + b) * Fd + f] = f2bf(t[tx][ty + i]);
  }
}

// ---------- transpose-convert [1024][4096] f32 -> perm[4096][1024] bf16 ----------
// dest row = gate-interleaved column: np = (n&1023)*4 + (n>>10)
__global__ void k_tw(const float* __restrict__ in, unsigned short* __restrict__ out) {
  __shared__ float t[32][33];
  int n0 = blockIdx.x * 32, k0 = blockIdx.y * 32;
  int tx = threadIdx.x & 31, ty = threadIdx.x >> 5;
#pragma unroll
  for (int i = 0; i < 32; i += 8)
    t[ty + i][tx] = in[(size_t)(k0 + ty + i) * G4 + n0 + tx];
  __syncthreads();
#pragma unroll
  for (int i = 0; i < 32; i += 8) {
    int n = n0 + ty + i;
    int np = ((n & 1023) << 2) | (n >> 10);
    out[(size_t)np * 1024 + k0 + tx] = f2bf(t[tx][ty + i]);
  }
}

__global__ void k_zero(unsigned int* p, int n) {
  int i = blockIdx.x * 256 + threadIdx.x;
  if (i < n) p[i] = 0u;
}

// ---------- GEMM: C[16384][4096] bf16 = A[16384][1024] x Bt[4096][1024]^T ----------
// Bt = Wperm (rows are interleaved gatecols) -> C cols land interleaved too.
__launch_bounds__(256, 2)
__global__ void k_gemm(const unsigned short* __restrict__ A,
                       const unsigned short* __restrict__ Bt,
                       unsigned short* __restrict__ C) {
  __shared__ unsigned short a_lds[128 * 64];
  __shared__ unsigned short b_lds[128 * 64];
  int bid = blockIdx.x;
  int tm = bid & 127, tn = bid >> 7;
  int tid = threadIdx.x, w = tid >> 6, l = tid & 63;
  int wm = w >> 1, wn = w & 1;
  f32x4 acc[4][4] = {};
  const unsigned short* Ab = A + (size_t)(tm * 128) * 1024;
  const unsigned short* Bb = Bt + (size_t)(tn * 128) * 1024;
  for (int kt = 0; kt < 16; ++kt) {
#pragma unroll
    for (int i = 0; i < 4; ++i) {
      int ci = tid + i * 256;
      int row = ci >> 3;
      int kB = (ci & 7) * 16;
      short8 va = *(const short8*)((const char*)(Ab + (size_t)row * 1024 + kt * 64) + kB);
      short8 vb = *(const short8*)((const char*)(Bb + (size_t)row * 1024 + kt * 64) + kB);
      int dst = row * 128 + (kB ^ ((row & 7) << 4));
      *(short8*)((char*)a_lds + dst) = va;
      *(short8*)((char*)b_lds + dst) = vb;
    }
    __syncthreads();
#pragma unroll
    for (int kb = 0; kb < 2; ++kb) {
      short8 af[4], bfv[4];
      int kByte = (kb * 32 + ((l >> 4) << 3)) * 2;
#pragma unroll
      for (int mi = 0; mi < 4; ++mi) {
        int row = wm * 64 + mi * 16 + (l & 15);
        af[mi] = *(const short8*)((const char*)a_lds + row * 128 + (kByte ^ ((row & 7) << 4)));
      }
#pragma unroll
      for (int ni = 0; ni < 4; ++ni) {
        int row = wn * 64 + ni * 16 + (l & 15);
        bfv[ni] = *(const short8*)((const char*)b_lds + row * 128 + (kByte ^ ((row & 7) << 4)));
      }
#pragma unroll
      for (int mi = 0; mi < 4; ++mi)
#pragma unroll
        for (int ni = 0; ni < 4; ++ni)
          acc[mi][ni] = mfma16(af[mi], bfv[ni], acc[mi][ni]);
    }
    __syncthreads();
  }
#pragma unroll
  for (int mi = 0; mi < 4; ++mi)
#pragma unroll
    for (int ni = 0; ni < 4; ++ni)
#pragma unroll
      for (int r = 0; r < 4; ++r) {
        int m = tm * 128 + wm * 64 + mi * 16 + ((l >> 4) << 2) + r;
        int n = tn * 128 + wn * 64 + ni * 16 + (l & 15);
        C[(size_t)m * G4 + n] = f2bf(acc[mi][ni][r]);
      }
}

// ---------- recurrence ----------
// 128 blocks: rg = bid&3 (16 batch), ch = bid>>2 (32 hidden cols).
// 8 waves; wave w owns j-quad [ch*32+w*4, +4) for all 16 batch rows.
// MFMA: A = Uperm tile (16 interleaved gatecols x K), B = h^T ->
// lane l holds gates i,f,g,o (regs r=0..3) for (b=l&15, j=j0+(l>>4)):
// pointwise fully in-register, no gate LDS, 2 barriers/step.
// U fragments pinned in VGPRs via inline-asm loads (no remat possible).
__launch_bounds__(512, 2)
__global__ void k_rec(const unsigned short* __restrict__ xs,
                      const unsigned short* __restrict__ xWb,
                      const unsigned short* __restrict__ Uperm,
                      const float* __restrict__ bias,
                      unsigned int* __restrict__ hbuf,  // [2][64][512] dwords
                      unsigned int* __restrict__ tags,  // [4][32][8]
                      float* __restrict__ out) {
  __shared__ unsigned short h_lds[16 * 1024];  // 32KB swizzled
  __shared__ float obuf[512][9];               // 18KB out staging
  int bid = blockIdx.x;
  int rg = bid & 3, ch = bid >> 2;
  int tid = threadIdx.x, w = tid >> 6, l = tid & 63;

  int jglob = ch * 32 + w * 4 + (l >> 4);   // this lane's hidden col
  int b = rg * 16 + (l & 15);               // this lane's batch row
  int gcbase = ch * 128 + w * 16;           // wave's interleaved-gatecol base

  // ---- pin U fragments in VGPRs (asm outputs cannot be rematerialized)
  const unsigned short* up =
      Uperm + (size_t)(gcbase + (l & 15)) * 1024 + ((l >> 4) << 3);
  short8 ufr[32];
#pragma unroll
  for (int kb = 0; kb < 32; ++kb) {
    asm volatile("global_load_dwordx4 %0, %1, off"
                 : "=v"(ufr[kb]) : "v"(up + kb * 32));
  }
  asm volatile("s_waitcnt vmcnt(0)" ::: "memory");

  float bias_r[4];
#pragma unroll
  for (int r = 0; r < 4; ++r) bias_r[r] = bias[r * 1024 + jglob];

  unsigned int* mytags = tags + rg * 256;
  unsigned int* mytag = mytags + ch * 8 + w;

  for (int t = 0; t < Seq; ++t) {
    // prefetch xW (4 gates, one 8B load) and x_t (cached; hide under spin)
    u32x2 xwp = *(const u32x2*)(xWb + ((size_t)(t * 64) + b) * G4 + (jglob << 2));
    float xt = bf2f(xs[((size_t)t * 64 + b) * Fd + jglob]);

    f32x4 acc0 = {0.f, 0.f, 0.f, 0.f}, acc1 = {0.f, 0.f, 0.f, 0.f};
    if (t > 0) {
      // wait for all 8 waves of all 32 producer blocks of this rowgroup
      if (tid < 32) {
        const unsigned int* tp = mytags + tid * 8;
        for (;;) {
          u32x4 ta, tb;
          asm volatile(
              "global_load_dwordx4 %0, %2, off sc0 sc1\n\t"
              "global_load_dwordx4 %1, %2, off offset:16 sc0 sc1\n\t"
              "s_waitcnt vmcnt(0)"
              : "=&v"(ta), "=&v"(tb) : "v"(tp) : "memory");
          unsigned int m = umin2(umin2(umin2(ta[0], ta[1]), umin2(ta[2], ta[3])),
                                 umin2(umin2(tb[0], tb[1]), umin2(tb[2], tb[3])));
          if (m >= (unsigned int)t) break;
        }
      }
      __syncthreads();
      // coherent read of h(t-1): 16 rows x 512 dwords = 32KB, 64B/thread
      const unsigned int* hp = hbuf + (((t & 1) ^ 1) << 15) + (rg << 13);
      u32x4 h0, h1, h2, h3;
      ld4x4_sys(hp + tid * 4, hp + 2048 + tid * 4, hp + 4096 + tid * 4,
                hp + 6144 + tid * 4, h0, h1, h2, h3);
      {
        int c0 = tid;        int r0 = c0 >> 7, b0 = (c0 & 127) * 16;
        *(u32x4*)((char*)h_lds + r0 * 2048 + (b0 ^ ((r0 & 7) << 4))) = h0;
        int c1 = tid + 512;  int r1 = c1 >> 7, b1 = (c1 & 127) * 16;
        *(u32x4*)((char*)h_lds + r1 * 2048 + (b1 ^ ((r1 & 7) << 4))) = h1;
        int c2 = tid + 1024; int r2 = c2 >> 7, b2 = (c2 & 127) * 16;
        *(u32x4*)((char*)h_lds + r2 * 2048 + (b2 ^ ((r2 & 7) << 4))) = h2;
        int c3 = tid + 1536; int r3 = c3 >> 7, b3 = (c3 & 127) * 16;
        *(u32x4*)((char*)h_lds + r3 * 2048 + (b3 ^ ((r3 & 7) << 4))) = h3;
      }
      __syncthreads();
      // gates^T = Uperm-tile @ h^T : 32 MFMAs, 2 independent chains
      int brow = l & 15;
      const char* bbase = (const char*)h_lds + brow * 2048;
      int sw = (brow & 7) << 4;
      int kres = (l >> 4) << 4;
#pragma unroll
      for (int kb = 0; kb < 32; kb += 2) {
        short8 b0 = *(const short8*)(bbase + ((kb * 64 + kres) ^ sw));
        acc0 = mfma16(ufr[kb], b0, acc0);
        short8 b1 = *(const short8*)(bbase + (((kb + 1) * 64 + kres) ^ sw));
        acc1 = mfma16(ufr[kb + 1], b1, acc1);
      }
    }
    // gates + pointwise, fully in-register (r = 0:i 1:f 2:g 3:o)
    float gi = acc0[0] + acc1[0] + bf2f((unsigned short)(xwp[0] & 0xffffu)) + bias_r[0];
    float gf = acc0[1] + acc1[1] + bf2f((unsigned short)(xwp[0] >> 16)) + bias_r[1];
    float gg = acc0[2] + acc1[2] + bf2f((unsigned short)(xwp[1] & 0xffffu)) + bias_r[2];
    float go = acc0[3] + acc1[3] + bf2f((unsigned short)(xwp[1] >> 16)) + bias_r[3];
    float si = sigm(gi), sf = sigm(gf), tg = tanhfast(gg), so = sigm(go);
    float cval = sf * xt + si * tg;
    float hval = so * tanhfast(cval);
    // publish h: pack 4 j-cols per batch row via shuffles, 8B store (lanes<16)
    unsigned int hb = f2bf(hval);
    unsigned int p1 = (unsigned int)__shfl((int)hb, (l & 15) + 16);
    unsigned int p2 = (unsigned int)__shfl((int)hb, (l & 15) + 32);
    unsigned int p3 = (unsigned int)__shfl((int)hb, (l & 15) + 48);
    if (l < 16) {
      u32x2 d; d[0] = hb | (p1 << 16); d[1] = p2 | (p3 << 16);
      unsigned int* hp2 = hbuf + ((t & 1) << 15) +
                          (unsigned)(rg * 16 + l) * 512 + (ch * 16 + w * 2);
      asm volatile("global_store_dwordx2 %0, %1, off sc0 sc1"
                   :: "v"(hp2), "v"(d) : "memory");
    }
    // release: drain this wave's coherent stores, then bump this wave's tag
    asm volatile("s_waitcnt vmcnt(0)" ::: "memory");
    if (l == 0)
      asm volatile("global_store_dword %0, %1, off sc0 sc1"
                   :: "v"(mytag), "v"((unsigned int)(t + 1)) : "memory");
    // off the tag critical path: staging + flush + finals
    obuf[tid][t & 7] = hval;
    if ((t & 7) == 7) {
      float* dst = out + ((size_t)b * 1024 + jglob) * Seq + (t - 7);
#pragma unroll
      for (int q = 0; q < 2; ++q) {
        f32x4 v = {obuf[tid][q * 4], obuf[tid][q * 4 + 1],
                   obuf[tid][q * 4 + 2], obuf[tid][q * 4 + 3]};
        *(f32x4*)(dst + q * 4) = v;
      }
    }
    if (t == Seq - 1) {
      out[(size_t)16777216 + (size_t)b * 1024 + jglob] = hval;
      out[(size_t)16777216 + 65536 + (size_t)b * 1024 + jglob] = cval;
    }
  }
}

extern "C" void kernel_launch(void* const* d_in, const int* in_sizes, int n_in,
                              void* d_out, int out_size, void* d_ws, size_t ws_size,
                              hipStream_t stream) {
  const float* x    = (const float*)d_in[0];
  const float* W    = (const float*)d_in[1];
  const float* U    = (const float*)d_in[2];
  const float* bias = (const float*)d_in[3];
  float* out = (float*)d_out;
  char* ws = (char*)d_ws;

  unsigned short* xs    = (unsigned short*)(ws);                       // 32 MB
  unsigned short* Wperm = (unsigned short*)(ws + (size_t)33554432);    // 8 MB
  unsigned short* Uperm = (unsigned short*)(ws + (size_t)41943040);    // 8 MB
  unsigned short* xWb   = (unsigned short*)(ws + (size_t)50331648);    // 128 MB
  unsigned int* hbuf    = (unsigned int*)(ws + (size_t)184549376);     // 256 KB
  unsigned int* tags    = (unsigned int*)(ws + (size_t)184811520);     // 4 KB

  k_tx<<<dim3(Seq / 32, Fd / 32, Bsz), 256, 0, stream>>>(x, xs);
  k_tw<<<dim3(G4 / 32, 1024 / 32), 256, 0, stream>>>(W, Wperm);
  k_tw<<<dim3(G4 / 32, 1024 / 32), 256, 0, stream>>>(U, Uperm);
  k_zero<<<4, 256, 0, stream>>>(tags, 1024);
  k_gemm<<<dim3((Mrows / 128) * (G4 / 128)), 256, 0, stream>>>(xs, Wperm, xWb);
  k_rec<<<dim3(128), 512, 0, stream>>>(xs, xWb, Uperm, bias, hbuf, tags, out);
}